// Round 8
// baseline (231.231 us; speedup 1.0000x reference)
//
#include <hip/hip_runtime.h>

typedef unsigned short u16;
typedef unsigned int u32;
typedef __bf16 bf16x8 __attribute__((ext_vector_type(8)));
typedef float f32x4 __attribute__((ext_vector_type(4)));
typedef u16 u16x4 __attribute__((ext_vector_type(4)));

#define GL2LDS16(g, l)                                                         \
    __builtin_amdgcn_global_load_lds(                                          \
        (__attribute__((address_space(1))) const void*)(g),                    \
        (__attribute__((address_space(3))) void*)(l), 16, 0, 0)

#define SYNC_VM(n) asm volatile("s_waitcnt vmcnt(" #n ")\ns_barrier" ::: "memory")
#define BAR()      asm volatile("s_barrier" ::: "memory")

// ---------- helpers ----------
__device__ __forceinline__ u16 f2bf(float f) {
    union { float f; u32 u; } x; x.f = f;
    u32 r = x.u + 0x7FFFu + ((x.u >> 16) & 1u);   // RNE (no NaNs here)
    return (u16)(r >> 16);
}

// pack 2 floats -> 2 bf16 in one u32 (round-half-up; lo=f0, hi=f1)
__device__ __forceinline__ u32 pack2bf(float f0, float f1) {
    union { float f; u32 u; } a, b;
    a.f = f0; b.f = f1;
    return __builtin_amdgcn_perm(b.u + 0x8000u, a.u + 0x8000u, 0x07060302u);
}

__device__ __forceinline__ float bits2f(u32 u) {
    union { u32 u; float f; } x; x.u = u; return x.f;
}

// fold softmax scale * log2(e) into Q fragments (scores then used with exp2)
__device__ __forceinline__ bf16x8 scale_frag(bf16x8 v) {
#pragma unroll
    for (int i = 0; i < 8; ++i) v[i] = (__bf16)((float)v[i] * 0.1803368801f);
    return v;
}

// ---------- fused fp32 -> bf16 convert (x | qkv | wo -> contiguous ws) ----------
__global__ __launch_bounds__(256) void convert_all_kernel(const float* __restrict__ x,
                                                          const float* __restrict__ qkv,
                                                          const float* __restrict__ wo,
                                                          u16* __restrict__ out) {
    int i = (blockIdx.x * 256 + threadIdx.x) * 4;
    const float* src;
    int off;
    if (i < 4194304)      { src = x;   off = i; }
    else if (i < 7340032) { src = qkv; off = i - 4194304; }
    else                  { src = wo;  off = i - 7340032; }
    float4 v = *(const float4*)(src + off);
    u16x4 o;
    o.x = f2bf(v.x); o.y = f2bf(v.y); o.z = f2bf(v.z); o.w = f2bf(v.w);
    *(u16x4*)(out + i) = o;
}

// ---------- GEMM: C[M,N] = A[M,K] * B[N,K]^T, bf16, double-buffered pipeline ----------
// FUSE_VT: blocks with n0 >= 2048 (V columns of QKV proj) write ONLY the
// transposed copy VtG[(b*16+h)*64+dh][s] (QKVo V-cols are left unwritten and
// later reused as split-1 partial storage).
template <int TM, bool OUT_BF16, bool FUSE_VT>
__global__ __launch_bounds__(256) void gemm_bt(const u16* __restrict__ A,
                                               const u16* __restrict__ B,
                                               void* __restrict__ Cout,
                                               u16* __restrict__ VtG,
                                               int M, int N, int K) {
    constexpr int MI = TM / 32;
    __shared__ u16 As[2][TM * 32];
    __shared__ u16 Bs[2][128 * 32];
    const int tid = threadIdx.x;
    const int w = tid >> 6, lane = tid & 63, ln = lane & 15, qd = lane >> 4;
    const int wr = w >> 1, wc = w & 1;
    const int m0 = blockIdx.y * TM, n0 = blockIdx.x * 128;

    const int srow = tid >> 2, scol = (tid & 3) * 8;
    const u16* Abase = A + (size_t)(m0 + srow) * K + scol;
    const u16* Bbase = B + (size_t)(n0 + srow) * K + scol;

    f32x4 acc[MI][4] = {};
    const int nsteps = K >> 5;

#pragma unroll
    for (int it = 0; it < TM / 64; ++it)
        GL2LDS16(Abase + (size_t)(it * 64) * K, &As[0][(tid + it * 256) * 8]);
#pragma unroll
    for (int it = 0; it < 2; ++it)
        GL2LDS16(Bbase + (size_t)(it * 64) * K, &Bs[0][(tid + it * 256) * 8]);

    for (int s = 0; s < nsteps; ++s) {
        const u16* Ab = As[s & 1];
        const u16* Bb = Bs[s & 1];
        if (s + 1 < nsteps) {
            const int nk = (s + 1) << 5;
            const int nb = (s + 1) & 1;
#pragma unroll
            for (int it = 0; it < TM / 64; ++it)
                GL2LDS16(Abase + (size_t)(it * 64) * K + nk, &As[nb][(tid + it * 256) * 8]);
#pragma unroll
            for (int it = 0; it < 2; ++it)
                GL2LDS16(Bbase + (size_t)(it * 64) * K + nk, &Bs[nb][(tid + it * 256) * 8]);
            if constexpr (TM == 128) SYNC_VM(4); else SYNC_VM(3);
        } else {
            SYNC_VM(0);
        }

        bf16x8 af[MI], bfr[4];
#pragma unroll
        for (int i = 0; i < MI; ++i)
            af[i] = *(const bf16x8*)&Ab[(wr * (TM / 2) + i * 16 + ln) * 32 + qd * 8];
#pragma unroll
        for (int j = 0; j < 4; ++j)
            bfr[j] = *(const bf16x8*)&Bb[(wc * 64 + j * 16 + ln) * 32 + qd * 8];
#pragma unroll
        for (int i = 0; i < MI; ++i)
#pragma unroll
            for (int j = 0; j < 4; ++j)
                acc[i][j] = __builtin_amdgcn_mfma_f32_16x16x32_bf16(af[i], bfr[j], acc[i][j], 0, 0, 0);
        BAR();
    }

    if (FUSE_VT && n0 >= 2048) {
        // transposed V store: VtG[(b*16+h)*64 + dh][s]
        const int bq = m0 >> 11;
        const int sl = (m0 & 2047) + wr * (TM / 2) + qd * 4;
#pragma unroll
        for (int i = 0; i < MI; ++i)
#pragma unroll
            for (int j = 0; j < 4; ++j) {
                int d = n0 - 2048 + wc * 64 + j * 16 + ln;
                int vrow = (bq * 16 + (d >> 6)) * 64 + (d & 63);
                u16x4 ov;
                ov.x = f2bf(acc[i][j][0]); ov.y = f2bf(acc[i][j][1]);
                ov.z = f2bf(acc[i][j][2]); ov.w = f2bf(acc[i][j][3]);
                *(u16x4*)&VtG[(size_t)vrow * 2048 + sl + i * 16] = ov;
            }
        return;
    }

#pragma unroll
    for (int i = 0; i < MI; ++i)
#pragma unroll
        for (int j = 0; j < 4; ++j)
#pragma unroll
            for (int r = 0; r < 4; ++r) {
                int row = m0 + wr * (TM / 2) + i * 16 + qd * 4 + r;
                int col = n0 + wc * 64 + j * 16 + ln;
                float v = acc[i][j][r];
                if constexpr (OUT_BF16)
                    ((u16*)Cout)[(size_t)row * N + col] = f2bf(v);
                else
                    ((float*)Cout)[(size_t)row * N + col] = v;
            }
}

// ---------- flash attention (causal), band-per-wave T=4, split-2 ----------
// Block g (=7-(x>>1)) covers bands {4g..4g+3} (64 q each); wave w owns band
// 4g+w entirely (4 tiles of 16 q) -> every K/V fragment feeds 4 MFMAs and
// activity is wave-uniform (act = c <= band). Split k handles chunks
// c = k, k+2, ... Transposed scores (S^T = K Q^T), no-max exp2 softmax
// (scale folded into Q), K via GL2LDS double-buffer (XOR swizzle), V frags
// read directly from global VtG, P via per-wave LDS (sequential reuse).
// Partials: split 0 -> AO, split 1 -> QKVo V-cols (stride 3072); l -> Lp.
__global__ __launch_bounds__(256) void attn_kernel(u16* __restrict__ QKV,
                                                   const u16* __restrict__ VtG,
                                                   u16* __restrict__ AO,
                                                   float* __restrict__ Lp) {
    __shared__ u16 Ks[2][64 * 64];     // [key][dh], swizzled
    __shared__ u16 Pls[4][16 * 64];    // per wave P[q][key], swizzled, tile-sequential

    const int tid = threadIdx.x;
    const int w = tid >> 6, lane = tid & 63, ln = lane & 15, qd = lane >> 4;
    const int b = blockIdx.z, h = blockIdx.y;
    const int g = 7 - (blockIdx.x >> 1);   // heavy blocks first
    const int k = blockIdx.x & 1;          // split
    const int Bw = 4 * g + w;              // this wave's band (0..31)
    const int q0 = Bw * 64;
    const int bh = b * 16 + h;
    const int swz = ln & 7;
    const int cMax = 4 * g + 3;            // block's last chunk

    // K staging: slot row = tid>>3 (0..31), swizzled source colgroup
    const int sr0 = tid >> 3;
    const int sg = (tid & 7) ^ (sr0 & 7);
    const u16* ksrc = QKV + (size_t)(b * 2048 + sr0) * 3072 + 1024 + h * 64 + sg * 8;
    GL2LDS16(ksrc + (size_t)(k * 64) * 3072, &Ks[0][tid * 8]);
    GL2LDS16(ksrc + (size_t)(k * 64 + 32) * 3072, &Ks[0][tid * 8 + 2048]);

    // Q B-frags for 4 tiles of this band, scale*log2e folded in
    bf16x8 qf[4][2];
#pragma unroll
    for (int i = 0; i < 4; ++i) {
        const u16* qp = QKV + (size_t)(b * 2048 + q0 + i * 16 + ln) * 3072 + h * 64;
        qf[i][0] = scale_frag(*(const bf16x8*)(qp + qd * 8));
        qf[i][1] = scale_frag(*(const bf16x8*)(qp + 32 + qd * 8));
    }

    const u16* vbase = VtG + (size_t)(bh * 64) * 2048;
    f32x4 o[4][4] = {};
    float l[4] = {};
    u16* Pw = Pls[w];

    for (int c = k; c <= cMax; c += 2) {
        const int buf = ((c - k) >> 1) & 1;
        if (c + 2 <= cMax) {
            GL2LDS16(ksrc + (size_t)((c + 2) * 64) * 3072, &Ks[buf ^ 1][tid * 8]);
            GL2LDS16(ksrc + (size_t)((c + 2) * 64 + 32) * 3072, &Ks[buf ^ 1][tid * 8 + 2048]);
            SYNC_VM(2);
        } else {
            SYNC_VM(0);
        }

        if (c <= Bw) {                      // wave-uniform activity
            const u16* Kb = Ks[buf];
            // V frags direct from global (issued early; used only in PV)
            bf16x8 vf[4][2];
#pragma unroll
            for (int dt = 0; dt < 4; ++dt) {
                const u16* vr = vbase + (size_t)(dt * 16 + ln) * 2048 + c * 64;
                vf[dt][0] = *(const bf16x8*)(vr + qd * 8);
                vf[dt][1] = *(const bf16x8*)(vr + 32 + qd * 8);
            }
            // K A-frags from swizzled LDS
            bf16x8 kf[4][2];
#pragma unroll
            for (int kt = 0; kt < 4; ++kt) {
                const u16* kr = Kb + (kt * 16 + ln) * 64;
                kf[kt][0] = *(const bf16x8*)(kr + ((qd ^ swz) * 8));
                kf[kt][1] = *(const bf16x8*)(kr + (((qd + 4) ^ swz) * 8));
            }

            bf16x8 pf[4][2];
#pragma unroll
            for (int i = 0; i < 4; ++i) {
                // ---- S^T = K Q^T : 8 MFMAs ----
                f32x4 s[4];
#pragma unroll
                for (int kt = 0; kt < 4; ++kt) {
                    f32x4 z = {0.f, 0.f, 0.f, 0.f};
                    z = __builtin_amdgcn_mfma_f32_16x16x32_bf16(kf[kt][0], qf[i][0], z, 0, 0, 0);
                    z = __builtin_amdgcn_mfma_f32_16x16x32_bf16(kf[kt][1], qf[i][1], z, 0, 0, 0);
                    s[kt] = z;
                }
                // ---- causal mask (diagonal chunk only) ----
                if (c == Bw) {
                    int myq = q0 + i * 16 + ln;
#pragma unroll
                    for (int kt = 0; kt < 4; ++kt)
#pragma unroll
                        for (int r = 0; r < 4; ++r) {
                            int key = c * 64 + kt * 16 + qd * 4 + r;
                            if (key > myq) s[kt][r] = -1e30f;
                        }
                }
                // ---- exp2 + l + pack -> per-wave LDS (tile-sequential reuse) ----
#pragma unroll
                for (int kt = 0; kt < 4; ++kt) {
                    float p0 = exp2f(s[kt][0]), p1 = exp2f(s[kt][1]);
                    float p2 = exp2f(s[kt][2]), p3 = exp2f(s[kt][3]);
                    l[i] += (p0 + p1) + (p2 + p3);
                    uint2 pk = {pack2bf(p0, p1), pack2bf(p2, p3)};
                    int gg = kt * 2 + (qd >> 1);
                    *(uint2*)&Pw[ln * 64 + ((gg ^ swz) * 8) + (qd & 1) * 4] = pk;
                }
                pf[i][0] = *(const bf16x8*)&Pw[ln * 64 + ((qd ^ swz) * 8)];
                pf[i][1] = *(const bf16x8*)&Pw[ln * 64 + (((qd + 4) ^ swz) * 8)];
            }

            // ---- O^T += V^T P^T : 32 MFMAs, each vf feeds 4 tiles ----
#pragma unroll
            for (int dt = 0; dt < 4; ++dt)
#pragma unroll
                for (int i = 0; i < 4; ++i) {
                    o[i][dt] = __builtin_amdgcn_mfma_f32_16x16x32_bf16(vf[dt][0], pf[i][0], o[i][dt], 0, 0, 0);
                    o[i][dt] = __builtin_amdgcn_mfma_f32_16x16x32_bf16(vf[dt][1], pf[i][1], o[i][dt], 0, 0, 0);
                }
        }
        BAR();   // protect Ks[buf] before it is re-staged
    }

    // ---- deferred l reductions; store UNNORMALIZED partials ----
    u16* Op = k ? (QKV + 2048) : AO;
    const size_t ost = k ? 3072 : 1024;
#pragma unroll
    for (int i = 0; i < 4; ++i) {
        float li = l[i];
        li += __shfl_xor(li, 16); li += __shfl_xor(li, 32);
        int myq = q0 + i * 16 + ln;
        if (qd == 0)
            Lp[(size_t)k * 65536 + (size_t)(b * 2048 + myq) * 16 + h] = li;
#pragma unroll
        for (int dt = 0; dt < 4; ++dt) {
            uint2 ov = {pack2bf(o[i][dt][0], o[i][dt][1]), pack2bf(o[i][dt][2], o[i][dt][3])};
            *(uint2*)&Op[(size_t)(b * 2048 + myq) * ost + h * 64 + dt * 16 + qd * 4] = ov;
        }
    }
}

// ---------- combine partials: AO = (Op0 + Op1) / (l0 + l1), in place ----------
__global__ __launch_bounds__(256) void normalize_kernel(u16* __restrict__ AO,
                                                        const u16* __restrict__ QKV,
                                                        const float* __restrict__ Lp) {
    int g = blockIdx.x * 256 + threadIdx.x;    // 524288 groups of 8 elems
    int row = g >> 7;
    int col = (g & 127) << 3;
    int h = col >> 6;
    float l = Lp[(size_t)row * 16 + h] + Lp[65536 + (size_t)row * 16 + h];
    float inv = 1.0f / l;
    u16* pa = AO + (size_t)row * 1024 + col;
    const u16* pb = QKV + (size_t)row * 3072 + 2048 + col;
    uint4 va = *(uint4*)pa;
    uint4 vb = *(const uint4*)pb;
    const u32* a = (const u32*)&va;
    const u32* bb = (const u32*)&vb;
    u32 res[4];
#pragma unroll
    for (int i = 0; i < 4; ++i) {
        float a0 = bits2f(a[i] << 16), a1 = bits2f(a[i] & 0xFFFF0000u);
        float b0 = bits2f(bb[i] << 16), b1 = bits2f(bb[i] & 0xFFFF0000u);
        res[i] = pack2bf((a0 + b0) * inv, (a1 + b1) * inv);
    }
    *(uint4*)pa = *(uint4*)&res[0];
}

// ---------- launch ----------
extern "C" void kernel_launch(void* const* d_in, const int* in_sizes, int n_in,
                              void* d_out, int out_size, void* d_ws, size_t ws_size,
                              hipStream_t stream) {
    const float* x   = (const float*)d_in[0];   // [2,2048,1024]
    const float* qkv = (const float*)d_in[1];   // [3072,1024]
    const float* wo  = (const float*)d_in[2];   // [1024,1024]
    float* out = (float*)d_out;                 // [2,2048,1024] fp32

    char* ws = (char*)d_ws;
    u16* xb    = (u16*)(ws + 0);            //  8 MB : x bf16 [4096,1024]
    u16* qkvb  = (u16*)(ws + 8388608);      //  6 MB : qkv bf16 (dead after gemm1)
    float* Lp  = (float*)(ws + 8388608);    //  512K: l partials [2][4096][16]
    u16* wob   = (u16*)(ws + 14680064);     //  2 MB : wo bf16 [1024,1024]
    u16* QKVo  = (u16*)(ws + 16777216);     // 24 MB : QKV bf16; V-cols = Op1 storage
    u16* AO    = (u16*)(ws + 41943040);     //  8 MB : attn out / Op0 [4096,1024]
    u16* VtG   = (u16*)(ws + 50331648);     //  8 MB : V^T [2*16*64, 2048]

    convert_all_kernel<<<8192, 256, 0, stream>>>(x, qkv, wo, xb);

    gemm_bt<128, true, true><<<dim3(24, 32), 256, 0, stream>>>(xb, qkvb, QKVo, VtG,
                                                               4096, 3072, 1024);

    attn_kernel<<<dim3(16, 16, 2), 256, 0, stream>>>(QKVo, VtG, AO, Lp);

    normalize_kernel<<<2048, 256, 0, stream>>>(AO, QKVo, Lp);

    gemm_bt<64, false, false><<<dim3(8, 64), 256, 0, stream>>>(AO, wob, out, nullptr,
                                                               4096, 1024, 1024);
}

// Round 9
// 187.486 us; speedup vs baseline: 1.2333x; 1.2333x over previous
//
#include <hip/hip_runtime.h>

typedef unsigned short u16;
typedef unsigned int u32;
typedef __bf16 bf16x8 __attribute__((ext_vector_type(8)));
typedef float f32x4 __attribute__((ext_vector_type(4)));
typedef u16 u16x4 __attribute__((ext_vector_type(4)));

#define GL2LDS16(g, l)                                                         \
    __builtin_amdgcn_global_load_lds(                                          \
        (__attribute__((address_space(1))) const void*)(g),                    \
        (__attribute__((address_space(3))) void*)(l), 16, 0, 0)

#define SYNC_VM(n) asm volatile("s_waitcnt vmcnt(" #n ")\ns_barrier" ::: "memory")
#define BAR()      asm volatile("s_barrier" ::: "memory")

// ---------- helpers ----------
__device__ __forceinline__ u16 f2bf(float f) {
    union { float f; u32 u; } x; x.f = f;
    u32 r = x.u + 0x7FFFu + ((x.u >> 16) & 1u);   // RNE (no NaNs here)
    return (u16)(r >> 16);
}

// pack 2 floats -> 2 bf16 in one u32 (round-half-up; lo=f0, hi=f1)
__device__ __forceinline__ u32 pack2bf(float f0, float f1) {
    union { float f; u32 u; } a, b;
    a.f = f0; b.f = f1;
    return __builtin_amdgcn_perm(b.u + 0x8000u, a.u + 0x8000u, 0x07060302u);
}

// fold softmax scale * log2(e) into Q fragments (scores then used with exp2)
__device__ __forceinline__ bf16x8 scale_frag(bf16x8 v) {
#pragma unroll
    for (int i = 0; i < 8; ++i) v[i] = (__bf16)((float)v[i] * 0.1803368801f);
    return v;
}

// ---------- fused fp32 -> bf16 convert (x | qkv | wo -> contiguous ws) ----------
__global__ __launch_bounds__(256) void convert_all_kernel(const float* __restrict__ x,
                                                          const float* __restrict__ qkv,
                                                          const float* __restrict__ wo,
                                                          u16* __restrict__ out) {
    int i = (blockIdx.x * 256 + threadIdx.x) * 4;
    const float* src;
    int off;
    if (i < 4194304)      { src = x;   off = i; }
    else if (i < 7340032) { src = qkv; off = i - 4194304; }
    else                  { src = wo;  off = i - 7340032; }
    float4 v = *(const float4*)(src + off);
    u16x4 o;
    o.x = f2bf(v.x); o.y = f2bf(v.y); o.z = f2bf(v.z); o.w = f2bf(v.w);
    *(u16x4*)(out + i) = o;
}

// ---------- GEMM: C[M,N] = A[M,K] * B[N,K]^T, bf16, double-buffered pipeline ----------
// FUSE_VT: blocks with n0 >= 2048 (V columns of the QKV projection) write ONLY
// the transposed copy VtG[(b*16+h)*64+dh][s] (QKVo V-cols left unwritten).
template <int TM, bool OUT_BF16, bool FUSE_VT>
__global__ __launch_bounds__(256) void gemm_bt(const u16* __restrict__ A,
                                               const u16* __restrict__ B,
                                               void* __restrict__ Cout,
                                               u16* __restrict__ VtG,
                                               int M, int N, int K) {
    constexpr int MI = TM / 32;
    __shared__ u16 As[2][TM * 32];
    __shared__ u16 Bs[2][128 * 32];
    const int tid = threadIdx.x;
    const int w = tid >> 6, lane = tid & 63, ln = lane & 15, qd = lane >> 4;
    const int wr = w >> 1, wc = w & 1;
    const int m0 = blockIdx.y * TM, n0 = blockIdx.x * 128;

    const int srow = tid >> 2, scol = (tid & 3) * 8;
    const u16* Abase = A + (size_t)(m0 + srow) * K + scol;
    const u16* Bbase = B + (size_t)(n0 + srow) * K + scol;

    f32x4 acc[MI][4] = {};
    const int nsteps = K >> 5;

#pragma unroll
    for (int it = 0; it < TM / 64; ++it)
        GL2LDS16(Abase + (size_t)(it * 64) * K, &As[0][(tid + it * 256) * 8]);
#pragma unroll
    for (int it = 0; it < 2; ++it)
        GL2LDS16(Bbase + (size_t)(it * 64) * K, &Bs[0][(tid + it * 256) * 8]);

    for (int s = 0; s < nsteps; ++s) {
        const u16* Ab = As[s & 1];
        const u16* Bb = Bs[s & 1];
        if (s + 1 < nsteps) {
            const int nk = (s + 1) << 5;
            const int nb = (s + 1) & 1;
#pragma unroll
            for (int it = 0; it < TM / 64; ++it)
                GL2LDS16(Abase + (size_t)(it * 64) * K + nk, &As[nb][(tid + it * 256) * 8]);
#pragma unroll
            for (int it = 0; it < 2; ++it)
                GL2LDS16(Bbase + (size_t)(it * 64) * K + nk, &Bs[nb][(tid + it * 256) * 8]);
            if constexpr (TM == 128) SYNC_VM(4); else SYNC_VM(3);
        } else {
            SYNC_VM(0);
        }

        bf16x8 af[MI], bfr[4];
#pragma unroll
        for (int i = 0; i < MI; ++i)
            af[i] = *(const bf16x8*)&Ab[(wr * (TM / 2) + i * 16 + ln) * 32 + qd * 8];
#pragma unroll
        for (int j = 0; j < 4; ++j)
            bfr[j] = *(const bf16x8*)&Bb[(wc * 64 + j * 16 + ln) * 32 + qd * 8];
#pragma unroll
        for (int i = 0; i < MI; ++i)
#pragma unroll
            for (int j = 0; j < 4; ++j)
                acc[i][j] = __builtin_amdgcn_mfma_f32_16x16x32_bf16(af[i], bfr[j], acc[i][j], 0, 0, 0);
        BAR();
    }

    if (FUSE_VT && n0 >= 2048) {
        // transposed V store: VtG[(b*16+h)*64 + dh][s]
        const int bq = m0 >> 11;
        const int sl = (m0 & 2047) + wr * (TM / 2) + qd * 4;
#pragma unroll
        for (int i = 0; i < MI; ++i)
#pragma unroll
            for (int j = 0; j < 4; ++j) {
                int d = n0 - 2048 + wc * 64 + j * 16 + ln;
                int vrow = (bq * 16 + (d >> 6)) * 64 + (d & 63);
                u16x4 ov;
                ov.x = f2bf(acc[i][j][0]); ov.y = f2bf(acc[i][j][1]);
                ov.z = f2bf(acc[i][j][2]); ov.w = f2bf(acc[i][j][3]);
                *(u16x4*)&VtG[(size_t)vrow * 2048 + sl + i * 16] = ov;
            }
        return;
    }

#pragma unroll
    for (int i = 0; i < MI; ++i)
#pragma unroll
        for (int j = 0; j < 4; ++j)
#pragma unroll
            for (int r = 0; r < 4; ++r) {
                int row = m0 + wr * (TM / 2) + i * 16 + qd * 4 + r;
                int col = n0 + wc * 64 + j * 16 + ln;
                float v = acc[i][j][r];
                if constexpr (OUT_BF16)
                    ((u16*)Cout)[(size_t)row * N + col] = f2bf(v);
                else
                    ((float*)Cout)[(size_t)row * N + col] = v;
            }
}

// ---------- flash attention (causal): r5 structure (best measured) ----------
// 256 thr = 4 waves, paired 64-q tiles (qtA = blockIdx.x light, qtB = 31-qtA
// heavy): uniform 33 tile-chunks/block, K/V staged once per block for both
// tiles. Transposed scores (S^T = K Q^T) so each lane owns one q column;
// no-max exp2 softmax (scale*log2e folded into Q); GL2LDS double-buffered
// K/V with XOR-swizzled LDS; single per-wave P buffer reused B then A
// (same-wave in-order DS). In-kernel normalization.
__global__ __launch_bounds__(256) void attn_kernel(const u16* __restrict__ QKV,
                                                   const u16* __restrict__ VtG,
                                                   u16* __restrict__ AO) {
    __shared__ u16 Ks[2][64 * 64];     // [key][dh], swizzled
    __shared__ u16 Vts[2][64 * 64];    // [dh][key], swizzled
    __shared__ u16 Pls[4][16 * 64];    // per wave P[q][key], swizzled, reused B->A

    const int tid = threadIdx.x;
    const int w = tid >> 6, lane = tid & 63, ln = lane & 15, qd = lane >> 4;
    const int b = blockIdx.z, h = blockIdx.y;
    const int qtA = blockIdx.x;        // 0..15 (light)
    const int qtB = 31 - qtA;          // 16..31 (heavy; block 0 heaviest, first)
    const int XA = qtA * 64 + w * 16, XB = qtB * 64 + w * 16;
    const int myqA = XA + ln, myqB = XB + ln;
    const int bh = b * 16 + h;
    const int swz = ln & 7;
    const int nch = qtB + 1;

    // staging: slot row = tid>>3 (0..31), swizzled source colgroup
    const int sr0 = tid >> 3;
    const int sg = (tid & 7) ^ (sr0 & 7);
    const u16* ksrc = QKV + (size_t)(b * 2048 + sr0) * 3072 + 1024 + h * 64 + sg * 8;
    const u16* vsrc = VtG + (size_t)(bh * 64 + sr0) * 2048 + sg * 8;

    GL2LDS16(ksrc, &Ks[0][tid * 8]);
    GL2LDS16(ksrc + (size_t)32 * 3072, &Ks[0][tid * 8 + 2048]);
    GL2LDS16(vsrc, &Vts[0][tid * 8]);
    GL2LDS16(vsrc + (size_t)32 * 2048, &Vts[0][tid * 8 + 2048]);

    // Q B-frags for both tiles, scale*log2e folded in
    const u16* qpA = QKV + (size_t)(b * 2048 + myqA) * 3072 + h * 64;
    const u16* qpB = QKV + (size_t)(b * 2048 + myqB) * 3072 + h * 64;
    bf16x8 qfA0 = scale_frag(*(const bf16x8*)(qpA + qd * 8));
    bf16x8 qfA1 = scale_frag(*(const bf16x8*)(qpA + 32 + qd * 8));
    bf16x8 qfB0 = scale_frag(*(const bf16x8*)(qpB + qd * 8));
    bf16x8 qfB1 = scale_frag(*(const bf16x8*)(qpB + 32 + qd * 8));

    f32x4 oA[4] = {}, oB[4] = {};
    float lA = 0.f, lB = 0.f;
    u16* Pw = Pls[w];

    for (int c = 0; c < nch; ++c) {
        if (c + 1 < nch) {
            const int k1 = (c + 1) * 64;
            const int nb = (c + 1) & 1;
            GL2LDS16(ksrc + (size_t)k1 * 3072, &Ks[nb][tid * 8]);
            GL2LDS16(ksrc + (size_t)(k1 + 32) * 3072, &Ks[nb][tid * 8 + 2048]);
            GL2LDS16(vsrc + k1, &Vts[nb][tid * 8]);
            GL2LDS16(vsrc + k1 + 32 * 2048, &Vts[nb][tid * 8 + 2048]);
            SYNC_VM(4);
        } else {
            SYNC_VM(0);
        }
        const u16* Kb = Ks[c & 1];
        const u16* Vb = Vts[c & 1];
        const bool actA = (c <= qtA);

        // ---- S^T = K Q^T, K frags shared between tiles ----
        f32x4 sA[4], sB[4];
#pragma unroll
        for (int kt = 0; kt < 4; ++kt) {
            const u16* kr = Kb + (kt * 16 + ln) * 64;
            bf16x8 kf0 = *(const bf16x8*)(kr + ((qd ^ swz) * 8));
            bf16x8 kf1 = *(const bf16x8*)(kr + (((qd + 4) ^ swz) * 8));
            f32x4 z = {0.f, 0.f, 0.f, 0.f};
            z = __builtin_amdgcn_mfma_f32_16x16x32_bf16(kf0, qfB0, z, 0, 0, 0);
            z = __builtin_amdgcn_mfma_f32_16x16x32_bf16(kf1, qfB1, z, 0, 0, 0);
            sB[kt] = z;
            if (actA) {
                f32x4 y = {0.f, 0.f, 0.f, 0.f};
                y = __builtin_amdgcn_mfma_f32_16x16x32_bf16(kf0, qfA0, y, 0, 0, 0);
                y = __builtin_amdgcn_mfma_f32_16x16x32_bf16(kf1, qfA1, y, 0, 0, 0);
                sA[kt] = y;
            }
        }

        // ---- tile B: mask (diagonal chunk only) + exp2 + pack ----
        if (c == qtB) {
#pragma unroll
            for (int kt = 0; kt < 4; ++kt)
#pragma unroll
                for (int r = 0; r < 4; ++r) {
                    int key = c * 64 + kt * 16 + qd * 4 + r;
                    if (key > myqB) sB[kt][r] = -1e30f;
                }
        }
#pragma unroll
        for (int kt = 0; kt < 4; ++kt) {
            float p0 = exp2f(sB[kt][0]), p1 = exp2f(sB[kt][1]);
            float p2 = exp2f(sB[kt][2]), p3 = exp2f(sB[kt][3]);
            lB += (p0 + p1) + (p2 + p3);
            uint2 pk = {pack2bf(p0, p1), pack2bf(p2, p3)};
            int g = kt * 2 + (qd >> 1);
            *(uint2*)&Pw[ln * 64 + ((g ^ swz) * 8) + (qd & 1) * 4] = pk;
        }
        bf16x8 pfB0 = *(const bf16x8*)&Pw[ln * 64 + ((qd ^ swz) * 8)];
        bf16x8 pfB1 = *(const bf16x8*)&Pw[ln * 64 + (((qd + 4) ^ swz) * 8)];

        // ---- tile A: same, reusing Pw (same-wave in-order DS => safe) ----
        bf16x8 pfA0, pfA1;
        if (actA) {
            if (c == qtA) {
#pragma unroll
                for (int kt = 0; kt < 4; ++kt)
#pragma unroll
                    for (int r = 0; r < 4; ++r) {
                        int key = c * 64 + kt * 16 + qd * 4 + r;
                        if (key > myqA) sA[kt][r] = -1e30f;
                    }
            }
#pragma unroll
            for (int kt = 0; kt < 4; ++kt) {
                float p0 = exp2f(sA[kt][0]), p1 = exp2f(sA[kt][1]);
                float p2 = exp2f(sA[kt][2]), p3 = exp2f(sA[kt][3]);
                lA += (p0 + p1) + (p2 + p3);
                uint2 pk = {pack2bf(p0, p1), pack2bf(p2, p3)};
                int g = kt * 2 + (qd >> 1);
                *(uint2*)&Pw[ln * 64 + ((g ^ swz) * 8) + (qd & 1) * 4] = pk;
            }
            pfA0 = *(const bf16x8*)&Pw[ln * 64 + ((qd ^ swz) * 8)];
            pfA1 = *(const bf16x8*)&Pw[ln * 64 + (((qd + 4) ^ swz) * 8)];
        }

        // ---- PV for both tiles, V frags shared ----
#pragma unroll
        for (int dt = 0; dt < 4; ++dt) {
            const u16* vr = Vb + (dt * 16 + ln) * 64;
            bf16x8 vf0 = *(const bf16x8*)(vr + ((qd ^ swz) * 8));
            bf16x8 vf1 = *(const bf16x8*)(vr + (((qd + 4) ^ swz) * 8));
            oB[dt] = __builtin_amdgcn_mfma_f32_16x16x32_bf16(vf0, pfB0, oB[dt], 0, 0, 0);
            oB[dt] = __builtin_amdgcn_mfma_f32_16x16x32_bf16(vf1, pfB1, oB[dt], 0, 0, 0);
            if (actA) {
                oA[dt] = __builtin_amdgcn_mfma_f32_16x16x32_bf16(vf0, pfA0, oA[dt], 0, 0, 0);
                oA[dt] = __builtin_amdgcn_mfma_f32_16x16x32_bf16(vf1, pfA1, oA[dt], 0, 0, 0);
            }
        }
        BAR();
    }

    // ---- deferred l reductions, normalize, packed stores ----
    lA += __shfl_xor(lA, 16); lA += __shfl_xor(lA, 32);
    lB += __shfl_xor(lB, 16); lB += __shfl_xor(lB, 32);
    float invA = 1.0f / lA, invB = 1.0f / lB;
#pragma unroll
    for (int dt = 0; dt < 4; ++dt) {
        uint2 ovA = {pack2bf(oA[dt][0] * invA, oA[dt][1] * invA),
                     pack2bf(oA[dt][2] * invA, oA[dt][3] * invA)};
        *(uint2*)&AO[(size_t)(b * 2048 + myqA) * 1024 + h * 64 + dt * 16 + qd * 4] = ovA;
        uint2 ovB = {pack2bf(oB[dt][0] * invB, oB[dt][1] * invB),
                     pack2bf(oB[dt][2] * invB, oB[dt][3] * invB)};
        *(uint2*)&AO[(size_t)(b * 2048 + myqB) * 1024 + h * 64 + dt * 16 + qd * 4] = ovB;
    }
}

// ---------- launch ----------
extern "C" void kernel_launch(void* const* d_in, const int* in_sizes, int n_in,
                              void* d_out, int out_size, void* d_ws, size_t ws_size,
                              hipStream_t stream) {
    const float* x   = (const float*)d_in[0];   // [2,2048,1024]
    const float* qkv = (const float*)d_in[1];   // [3072,1024]
    const float* wo  = (const float*)d_in[2];   // [1024,1024]
    float* out = (float*)d_out;                 // [2,2048,1024] fp32

    char* ws = (char*)d_ws;
    u16* xb    = (u16*)(ws + 0);            //  8 MB : x bf16 [4096,1024]
    u16* qkvb  = (u16*)(ws + 8388608);      //  6 MB : qkv bf16 [3072,1024]
    u16* wob   = (u16*)(ws + 14680064);     //  2 MB : wo bf16 [1024,1024]
    u16* QKVo  = (u16*)(ws + 16777216);     // 24 MB : QKV bf16 (V-cols unwritten)
    u16* AO    = (u16*)(ws + 41943040);     //  8 MB : attn out [4096,1024]
    u16* VtG   = (u16*)(ws + 50331648);     //  8 MB : V^T [2*16*64, 2048]

    convert_all_kernel<<<8192, 256, 0, stream>>>(x, qkv, wo, xb);

    gemm_bt<128, true, true><<<dim3(24, 32), 256, 0, stream>>>(xb, qkvb, QKVo, VtG,
                                                               4096, 3072, 1024);

    attn_kernel<<<dim3(16, 16, 2), 256, 0, stream>>>(QKVo, VtG, AO);

    gemm_bt<64, false, false><<<dim3(8, 64), 256, 0, stream>>>(AO, wob, out, nullptr,
                                                               4096, 1024, 1024);
}